// Round 9
// baseline (5707.568 us; speedup 1.0000x reference)
//
#include <hip/hip_runtime.h>
#include <cstdint>
#include <cstddef>

// ============================================================================
// LSTM forecaster, MI355X — R9: minimum-hop sentinel exchange, barrier-free
// tail. Evidence: R4 (sentinel) 3.42us/step ~= R8 (flag+drain+load) 3.59 =>
// period = MALL RT x hops + compute tail, not detection bookkeeping. R9 keeps
// the proven agent-scope sentinel data-poll (1 hop) and attacks the rest:
//  - poll pair reloaded unconditionally -> both loads in flight (1 RT period,
//    R4's selective reload serialized them at 2 RT);
//  - wave N-rows = 4 gates x 4 feats -> gate combine is 3 intra-wave
//    shfl_xor, publish straight from the wave (no 2nd barrier, no ex-LDS);
//  - A tile double-buffered by step parity -> exactly ONE __syncthreads/step
//    (cross-step reuse safe: block at t+2 implies all consumed t+1).
// ============================================================================

typedef __bf16 bf16x8 __attribute__((ext_vector_type(8)));
typedef float  f32x4  __attribute__((ext_vector_type(4)));

static constexpr unsigned long long SENT = 0x7FC07FC07FC07FC0ULL;  // 4x bf16 NaN

// ---- workspace layout (bytes) ----
static constexpr size_t SZ_HALL = (size_t)705 * 128 * 512 * 2;  // h slots 0..704
static constexpr size_t SZ_WCAT = (size_t)2048 * 576 * 2;       // [Whh | Wfuse] bf16
static constexpr size_t SZ_WIH  = (size_t)2048 * 512 * 2;       // Wih bf16 (AR phase)
static constexpr size_t SZ_DECW = (size_t)64 * 512 * 2;         // dec_W bf16
static constexpr size_t SZ_XT   = (size_t)512 * 128 * 64 * 2;   // x transposed [t][b][c]
static constexpr size_t OFF_HALL = 0;
static constexpr size_t OFF_WCAT = OFF_HALL + SZ_HALL;
static constexpr size_t OFF_WIH  = OFF_WCAT + SZ_WCAT;
static constexpr size_t OFF_DECW = OFF_WIH + SZ_WIH;
static constexpr size_t OFF_XT   = OFF_DECW + SZ_DECW;
static constexpr size_t OFF_B2   = OFF_XT + SZ_XT;              // 2048 f32
static constexpr size_t OFF_BAR_ = OFF_B2 + 2048 * 4;           // b_ar 2048 f32
static constexpr size_t WS_NEEDED = OFF_BAR_ + 2048 * 4;

__device__ __forceinline__ float sigm(float x) { return 1.f / (1.f + __expf(-x)); }
__device__ __forceinline__ float tanh_fast(float x) {
  return 1.f - 2.f / (__expf(2.f * x) + 1.f);  // correct +/-1 limits
}

// ---------------------------------------------------------------------------
// setup0: conversions + h slot0 zeros + NaN sentinel fill (mandatory: harness
// re-poisons ws with 0xAA, a legit bf16 value).
// ---------------------------------------------------------------------------
__global__ void __launch_bounds__(256)
setup0(const float* __restrict__ x, const float* __restrict__ Wih,
       const float* __restrict__ Whh, const float* __restrict__ bih,
       const float* __restrict__ bhh, const float* __restrict__ decW,
       __bf16* __restrict__ xT, __bf16* __restrict__ Wih_bf,
       __bf16* __restrict__ Wcat, __bf16* __restrict__ decW_bf,
       float* __restrict__ b_ar, __bf16* __restrict__ h_all)
{
  size_t gid = (size_t)blockIdx.x * blockDim.x + threadIdx.x;
  size_t gsz = (size_t)gridDim.x * blockDim.x;
  for (size_t i = gid; i < 4194304u; i += gsz) {          // xT[t][b][c] = x[b][t][c]
    size_t t = i >> 13, b = (i >> 6) & 127u, c = i & 63u;
    xT[i] = (__bf16)x[(b * 512 + t) * 64 + c];
  }
  for (size_t i = gid; i < 1048576u; i += gsz) Wih_bf[i] = (__bf16)Wih[i];
  for (size_t i = gid; i < 1048576u; i += gsz) {
    size_t r = i >> 9, k = i & 511u;
    Wcat[r * 576 + k] = (__bf16)Whh[i];                   // cols 0..511 = Whh
  }
  for (size_t i = gid; i < 32768u; i += gsz) decW_bf[i] = (__bf16)decW[i];
  for (size_t i = gid; i < 2048u; i += gsz) b_ar[i] = bih[i] + bhh[i];
  unsigned long long* hp = (unsigned long long*)h_all;
  for (size_t i = gid; i < 16384u; i += gsz) hp[i] = 0ULL;               // slot 0 = 0
  for (size_t i = 16384u + gid; i < 11550720u; i += gsz) hp[i] = SENT;   // slots 1..704
}

// ---------------------------------------------------------------------------
// setup1: Wfuse = Wih @ enc_W -> Wcat cols 512..575 ; b2 = bih+bhh+Wih@enc_b
// ---------------------------------------------------------------------------
__global__ void __launch_bounds__(64)
setup1(const float* __restrict__ Wih, const float* __restrict__ encW,
       const float* __restrict__ encb, const float* __restrict__ bih,
       const float* __restrict__ bhh, __bf16* __restrict__ Wcat,
       float* __restrict__ b2)
{
  int r = blockIdx.x;        // 0..2047
  int c = threadIdx.x;       // 0..63
  const float* wr = Wih + (size_t)r * 512;
  float acc = 0.f;
  for (int k = 0; k < 512; ++k) acc += wr[k] * encW[(size_t)k * 64 + c];
  Wcat[(size_t)r * 576 + 512 + c] = (__bf16)acc;
  float p = 0.f;
  for (int kk = 0; kk < 8; ++kk) { int k = kk * 64 + c; p += wr[k] * encb[k]; }
  for (int off = 32; off > 0; off >>= 1) p += __shfl_down(p, off);
  if (c == 0) b2[r] = bih[r] + bhh[r] + p;
}

// ---------------------------------------------------------------------------
// One LSTM step. block = 1024 thr (16 waves). Wave wv's 16 MFMA N-rows =
// {gate g, feature f0 + wv*4 + q} with n16 = g*4+q. Gate combine: shfl_xor
// (4,8,12) within the wave; publish: lanes g==0 write hs, lanes<16 store 8B.
// A is parity-selected by the caller (double buffer, one barrier per step).
// ---------------------------------------------------------------------------
template<bool MAIN>
__device__ __forceinline__ void lstm_step(
    unsigned t, int tid, int wv, int lane, int b0, int f0,
    const bf16x8 (&wf)[18], float bv,
    __bf16* __restrict__ h_all, const __bf16* __restrict__ xT,
    f32x4& creg, __bf16 (*A)[584], __bf16 (*hs)[16][4])
{
  const int n16 = lane & 15, quad = lane >> 4;
  const int g = n16 >> 2, q = n16 & 3;
  (void)q;

  // ---- x prefetch (plain cached load; in flight during the poll) ----
  uint4 xv;
  if (MAIN && tid < 128)
    xv = *(const uint4*)(xT + (size_t)(t - 1) * 8192 +
                         (size_t)(b0 + (tid >> 3)) * 64 + (tid & 7) * 8);

  // ---- poll h_{t-1}: 2 x 8B pieces, BOTH reloaded unconditionally so both
  //      stay in flight (poll period ~= 1 MALL RT, not 2) ----
  const unsigned long long* src = (const unsigned long long*)
      (h_all + (size_t)(t - 1) * 65536 + (size_t)(b0 + (tid >> 6)) * 512) +
      (size_t)(tid & 63) * 2;
  unsigned long long v0 = __hip_atomic_load(src,     __ATOMIC_RELAXED, __HIP_MEMORY_SCOPE_AGENT);
  unsigned long long v1 = __hip_atomic_load(src + 1, __ATOMIC_RELAXED, __HIP_MEMORY_SCOPE_AGENT);
  while (v0 == SENT || v1 == SENT) {
    v0 = __hip_atomic_load(src,     __ATOMIC_RELAXED, __HIP_MEMORY_SCOPE_AGENT);
    v1 = __hip_atomic_load(src + 1, __ATOMIC_RELAXED, __HIP_MEMORY_SCOPE_AGENT);
  }

  // ---- stage A (parity buffer) ----
  {
    unsigned long long* ad = (unsigned long long*)&A[tid >> 6][(tid & 63) * 8];
    ad[0] = v0; ad[1] = v1;
  }
  if (MAIN && tid < 128)
    *(uint4*)(&A[tid >> 3][512 + (tid & 7) * 8]) = xv;
  __syncthreads();   // the ONLY barrier per step

  // ---- MFMA: rows = 4 gates x 4 feats of this wave; bias in accumulator ----
  f32x4 a0 = {bv, bv, bv, bv}, a1 = {0.f, 0.f, 0.f, 0.f};
  {
    const __bf16* arow = &A[n16][quad * 8];
    #pragma unroll
    for (int kc = 0; kc < (MAIN ? 18 : 16); ++kc) {
      bf16x8 af = *(const bf16x8*)(arow + kc * 32);
      if (kc & 1) a1 = __builtin_amdgcn_mfma_f32_16x16x32_bf16(af, wf[kc], a1, 0, 0, 0);
      else        a0 = __builtin_amdgcn_mfma_f32_16x16x32_bf16(af, wf[kc], a0, 0, 0, 0);
    }
    a0 += a1;
  }

  // ---- gate combine in-wave: partners differ in g (n16 bits 2..3) ----
  float h2[4];
  #pragma unroll
  for (int j = 0; j < 4; ++j) {
    float own = a0[j];
    float s4  = __shfl_xor(own, 4);
    float s8  = __shfl_xor(own, 8);
    float s12 = __shfl_xor(own, 12);
    float vi = g == 0 ? own : (g == 1 ? s4  : (g == 2 ? s8  : s12));
    float vf = g == 0 ? s4  : (g == 1 ? own : (g == 2 ? s12 : s8 ));
    float vg = g == 0 ? s8  : (g == 1 ? s12 : (g == 2 ? own : s4 ));
    float vo = g == 0 ? s12 : (g == 1 ? s8  : (g == 2 ? s4  : own));
    float ig = sigm(vi);
    float gg = tanh_fast(vg);
    float og = sigm(vo);
    float c2;
    if (MAIN) { float fg = sigm(vf); c2 = fg * creg[j] + ig * gg; creg[j] = c2; }
    else      { c2 = ig * gg; }               // AR: zero state
    h2[j] = og * tanh_fast(c2);
  }

  // ---- wave-private pack (no barrier: same-wave LDS ordering) + publish ----
  if (g == 0) {                                // lanes n16 0..3: feature q
    #pragma unroll
    for (int j = 0; j < 4; ++j) hs[wv][quad * 4 + j][n16] = (__bf16)h2[j];
  }
  if (lane < 16) {                             // one 8B piece per batch row
    unsigned long long pk = *(const unsigned long long*)&hs[wv][lane][0];
    unsigned long long* dst = (unsigned long long*)
        (h_all + (size_t)t * 65536 + (size_t)(b0 + lane) * 512 + f0 + wv * 4);
    __hip_atomic_store(dst, pk, __ATOMIC_RELAXED, __HIP_MEMORY_SCOPE_AGENT);
  }
}

__global__ void __launch_bounds__(1024, 4)
lstm_persist(const __bf16* __restrict__ xT, const __bf16* __restrict__ Wcat,
             const __bf16* __restrict__ Wih_bf, const float* __restrict__ b2,
             const float* __restrict__ b_ar, __bf16* __restrict__ h_all)
{
  const int bid = blockIdx.x;                  // 64 blocks
  const int g8 = bid & 7, sub = bid >> 3;      // group (16 batches), 64 feats
  const int b0 = g8 * 16, f0 = sub * 64;
  const int tid = threadIdx.x;
  const int wv = tid >> 6, lane = tid & 63;
  const int n16 = lane & 15, quad = lane >> 4;
  const int g = n16 >> 2, q = n16 & 3;

  __shared__ __align__(16) __bf16 A[2][16][584];  // double-buffered A tile
  __shared__ __align__(8)  __bf16 hs[16][16][4];  // wave-private publish pack

  // persistent weight fragments: row = g*512 + f0 + wv*4 + q
  const int row = g * 512 + f0 + wv * 4 + q;
  bf16x8 wf[18];
  {
    const __bf16* wrow = Wcat + (size_t)row * 576 + quad * 8;
    #pragma unroll
    for (int kc = 0; kc < 18; ++kc) wf[kc] = *(const bf16x8*)(wrow + kc * 32);
  }
  float bvm = b2[row];

  f32x4 creg = {0.f, 0.f, 0.f, 0.f};   // cell state for (feature row, 4 batches)

  for (unsigned t = 1; t <= 512; ++t)
    lstm_step<true>(t, tid, wv, lane, b0, f0, wf, bvm, h_all, xT, creg,
                    A[t & 1], hs);

  { // AR phase: h feeds Wih with zero recurrent state
    const __bf16* wrow = Wih_bf + (size_t)row * 512 + quad * 8;
    #pragma unroll
    for (int kc = 0; kc < 16; ++kc) wf[kc] = *(const bf16x8*)(wrow + kc * 32);
  }
  float bva = b_ar[row];
  for (unsigned t = 513; t <= 704; ++t)
    lstm_step<false>(t, tid, wv, lane, b0, f0, wf, bva, h_all, xT, creg,
                     A[t & 1], hs);
}

// ---------------------------------------------------------------------------
// final_proj: out[b][j][c] = h_slot[j+2][b][:] @ dec_W.T + dec_b, j=0..702.
// ---------------------------------------------------------------------------
__global__ void __launch_bounds__(256)
final_proj(const __bf16* __restrict__ h_all, const __bf16* __restrict__ decW_bf,
           const float* __restrict__ decb, float* __restrict__ out)
{
  const int bi = blockIdx.x;               // 0..702
  const int tid = threadIdx.x;
  const int wv = tid >> 6, lane = tid & 63;
  const int n16 = lane & 15, quad = lane >> 4;
  const size_t r0 = 256 + (size_t)bi * 128 + (size_t)wv * 32;

  f32x4 acc[2][4];
  #pragma unroll
  for (int mt = 0; mt < 2; ++mt)
    #pragma unroll
    for (int nt = 0; nt < 4; ++nt) acc[mt][nt] = f32x4{0.f, 0.f, 0.f, 0.f};

  const __bf16* arow0 = h_all + (r0 + n16) * 512 + quad * 8;
  const __bf16* arow1 = arow0 + 16 * 512;
  const __bf16* brow  = decW_bf + (size_t)n16 * 512 + quad * 8;

  #pragma unroll
  for (int kc = 0; kc < 16; ++kc) {
    bf16x8 a0 = *(const bf16x8*)(arow0 + kc * 32);
    bf16x8 a1 = *(const bf16x8*)(arow1 + kc * 32);
    #pragma unroll
    for (int nt = 0; nt < 4; ++nt) {
      bf16x8 b = *(const bf16x8*)(brow + (size_t)nt * 8192 + kc * 32);
      acc[0][nt] = __builtin_amdgcn_mfma_f32_16x16x32_bf16(a0, b, acc[0][nt], 0, 0, 0);
      acc[1][nt] = __builtin_amdgcn_mfma_f32_16x16x32_bf16(a1, b, acc[1][nt], 0, 0, 0);
    }
  }
  #pragma unroll
  for (int mt = 0; mt < 2; ++mt)
    #pragma unroll
    for (int nt = 0; nt < 4; ++nt)
      #pragma unroll
      for (int r = 0; r < 4; ++r) {
        size_t R = r0 + mt * 16 + quad * 4 + r;      // h_all row
        int slot = (int)(R >> 7), b = (int)(R & 127);
        int j = slot - 2;
        int c = nt * 16 + n16;
        out[((size_t)b * 703 + j) * 64 + c] = acc[mt][nt][r] + decb[c];
      }
}

// ---------------------------------------------------------------------------
extern "C" void kernel_launch(void* const* d_in, const int* in_sizes, int n_in,
                              void* d_out, int out_size, void* d_ws, size_t ws_size,
                              hipStream_t stream)
{
  const float* x    = (const float*)d_in[0];
  const float* encW = (const float*)d_in[1];
  const float* encb = (const float*)d_in[2];
  const float* Wih  = (const float*)d_in[3];
  const float* Whh  = (const float*)d_in[4];
  const float* bih  = (const float*)d_in[5];
  const float* bhh  = (const float*)d_in[6];
  const float* decW = (const float*)d_in[7];
  const float* decb = (const float*)d_in[8];
  float* out = (float*)d_out;

  if (ws_size < WS_NEEDED) return;

  char* ws = (char*)d_ws;
  __bf16* h_all   = (__bf16*)(ws + OFF_HALL);
  __bf16* Wcat    = (__bf16*)(ws + OFF_WCAT);
  __bf16* Wih_bf  = (__bf16*)(ws + OFF_WIH);
  __bf16* decW_bf = (__bf16*)(ws + OFF_DECW);
  __bf16* xT      = (__bf16*)(ws + OFF_XT);
  float*  b2      = (float*)(ws + OFF_B2);
  float*  b_ar    = (float*)(ws + OFF_BAR_);

  hipLaunchKernelGGL(setup0, dim3(2048), dim3(256), 0, stream,
                     x, Wih, Whh, bih, bhh, decW, xT, Wih_bf, Wcat, decW_bf,
                     b_ar, h_all);
  hipLaunchKernelGGL(setup1, dim3(2048), dim3(64), 0, stream,
                     Wih, encW, encb, bih, bhh, Wcat, b2);
  hipLaunchKernelGGL(lstm_persist, dim3(64), dim3(1024), 0, stream,
                     xT, Wcat, Wih_bf, b2, b_ar, h_all);
  hipLaunchKernelGGL(final_proj, dim3(703), dim3(256), 0, stream,
                     h_all, decW_bf, decb, out);
}